// Round 13
// baseline (156.243 us; speedup 1.0000x reference)
//
#include <hip/hip_runtime.h>

#define NN 10000
#define NE 640000
#define D  128
#define SEG 32                   // slots per (node,XCD); Poisson(8) P(>=32) ~ 1e-10
#define PAD_SHIFT 8              // 256 slots/node = 8 segments x 32
#define GEMM_BLOCKS ((NN + 31) / 32)
#define CSTRIDE 10240            // per-XCD counter replica stride
#define COUNT_BLOCKS (NE / 1024) // 625 blocks x 256 thr x 4 edges

// physical XCD id of the wave (0..7 on MI355X). Uniform within a workgroup.
__device__ __forceinline__ int xcc_id() {
    unsigned x;
    asm volatile("s_getreg_b32 %0, hwreg(HW_REG_XCC_ID)" : "=s"(x));
    return (int)(x & 7);
}

// ---- zero the per-XCD counter replicas ----------------------------------

__global__ __launch_bounds__(256) void zero_kernel(int* __restrict__ p, int n) {
    int i = blockIdx.x * 256 + threadIdx.x;
    if (i < n) p[i] = 0;
}

// ---- fused: gemm1 + count&scatter (fixed per-XCD segments) --------------
// slot = (c<<8) + xcd*32 + local_rank : same thread does atomic AND store,
// 4-deep batching overlaps the atomic->store chains.

__global__ __launch_bounds__(256) void fused_gemm_cs_kernel(const float* __restrict__ X,
                                                            const float* __restrict__ W,
                                                            float* __restrict__ H,
                                                            const int* __restrict__ ei,
                                                            const float* __restrict__ ew,
                                                            int* __restrict__ cnt8,
                                                            int2* __restrict__ epack) {
    int bid = blockIdx.x;
    if (bid < GEMM_BLOCKS) {
        __shared__ float xs[32][D];
        int t  = threadIdx.x;
        int d  = t & 127;
        int rh = t >> 7;
        int r0 = bid * 32;
#pragma unroll
        for (int r = 0; r < 16; ++r) {
            int rr = r0 + rh * 16 + r;
            xs[rh * 16 + r][d] = (rr < NN) ? X[(size_t)rr * D + d] : 0.0f;
        }
        __syncthreads();
        float acc[16];
#pragma unroll
        for (int r = 0; r < 16; ++r) acc[r] = 0.0f;
        for (int k = 0; k < D; k += 4) {
            float w0 = W[(k + 0) * D + d];
            float w1 = W[(k + 1) * D + d];
            float w2 = W[(k + 2) * D + d];
            float w3 = W[(k + 3) * D + d];
#pragma unroll
            for (int r = 0; r < 16; ++r) {
                float4 xv = *reinterpret_cast<const float4*>(&xs[rh * 16 + r][k]);
                acc[r] = fmaf(xv.x, w0, acc[r]);
                acc[r] = fmaf(xv.y, w1, acc[r]);
                acc[r] = fmaf(xv.z, w2, acc[r]);
                acc[r] = fmaf(xv.w, w3, acc[r]);
            }
        }
#pragma unroll
        for (int r = 0; r < 16; ++r) {
            int rr = r0 + rh * 16 + r;
            if (rr < NN) H[(size_t)rr * D + d] = acc[r];
        }
    } else {
        int e0 = (bid - GEMM_BLOCKS) * 1024 + threadIdx.x;
        int x  = xcc_id();
        int* mycnt = cnt8 + x * CSTRIDE;
        int   c[4], s[4];
        float w[4];
#pragma unroll
        for (int k = 0; k < 4; ++k) {
            int e = e0 + k * 256;          // 625*1024 == NE exactly, no bounds check
            c[k] = ei[NE + e];
            s[k] = ei[e];
            w[k] = ew[e];
        }
        int lr[4];
#pragma unroll
        for (int k = 0; k < 4; ++k) lr[k] = atomicAdd(&mycnt[c[k]], 1);
#pragma unroll
        for (int k = 0; k < 4; ++k) {
            if (lr[k] < SEG) {             // overflow guard (P ~ 1e-10/pair)
                int2 v;
                v.x = s[k];
                v.y = __float_as_int(w[k]);
                epack[((size_t)c[k] << PAD_SHIFT) + x * SEG + lr[k]] = v;
            }
        }
    }
}

// ---- deg -> dinv from segmented CSR, wave per node ----------------------

__global__ __launch_bounds__(256) void degdinv_kernel(const int* __restrict__ cnt8,
                                                      const int2* __restrict__ epack,
                                                      float* __restrict__ dinv) {
    int node = blockIdx.x * 4 + (threadIdx.x >> 6);
    if (node >= NN) return;
    int lane = threadIdx.x & 63;
    const int2* base = epack + ((size_t)node << PAD_SHIFT);
    float s = 0.0f;
#pragma unroll
    for (int x = 0; x < 8; ++x) {
        int mx = cnt8[x * CSTRIDE + node];
        if (lane < mx) s += __int_as_float(base[x * SEG + lane].y);
    }
#pragma unroll
    for (int off = 32; off; off >>= 1) s += __shfl_down(s, off);
    if (lane == 0) dinv[node] = rsqrtf(s + 1.0f);      // +1 = self loop
}

// ---- plain gemm (layer 2): 32 rows/block, 256 threads -------------------

__global__ __launch_bounds__(256) void gemm_kernel(const float* __restrict__ X,
                                                   const float* __restrict__ W,
                                                   float* __restrict__ H) {
    __shared__ float xs[32][D];
    int t  = threadIdx.x;
    int d  = t & 127;
    int rh = t >> 7;
    int r0 = blockIdx.x * 32;
#pragma unroll
    for (int r = 0; r < 16; ++r) {
        int rr = r0 + rh * 16 + r;
        xs[rh * 16 + r][d] = (rr < NN) ? X[(size_t)rr * D + d] : 0.0f;
    }
    __syncthreads();
    float acc[16];
#pragma unroll
    for (int r = 0; r < 16; ++r) acc[r] = 0.0f;
    for (int k = 0; k < D; k += 4) {
        float w0 = W[(k + 0) * D + d];
        float w1 = W[(k + 1) * D + d];
        float w2 = W[(k + 2) * D + d];
        float w3 = W[(k + 3) * D + d];
#pragma unroll
        for (int r = 0; r < 16; ++r) {
            float4 xv = *reinterpret_cast<const float4*>(&xs[rh * 16 + r][k]);
            acc[r] = fmaf(xv.x, w0, acc[r]);
            acc[r] = fmaf(xv.y, w1, acc[r]);
            acc[r] = fmaf(xv.z, w2, acc[r]);
            acc[r] = fmaf(xv.w, w3, acc[r]);
        }
    }
#pragma unroll
    for (int r = 0; r < 16; ++r) {
        int rr = r0 + rh * 16 + r;
        if (rr < NN) H[(size_t)rr * D + d] = acc[r];
    }
}

// ---- aggregate: half-feature per block, XCD-parity mapped ---------------
// Block i -> (node c, half hh), i = (c/4)*8 + (c%4)*2 + hh: on round-robin
// blockIdx%8 -> XCD dispatch, even XCDs gather only H[:,0:64] (2.56MB),
// odd XCDs H[:,64:128] -> per-XCD gather set fits the 4MB L2.
// Stages the 8 segments; counts<=32 -> predicated single-step staging.

__global__ __launch_bounds__(64) void agg_half_kernel(const float* __restrict__ H,
                                                      const int* __restrict__ cnt8,
                                                      const int2* __restrict__ epack,
                                                      const float* __restrict__ dinv,
                                                      const float* __restrict__ bias,
                                                      float* __restrict__ out) {
    __shared__ int   s_src[256];
    __shared__ float s_n[256];
    int i    = blockIdx.x;
    int slot = i & 7;
    int hh   = slot & 1;
    int c    = (i >> 3) * 4 + (slot >> 1);
    int t    = threadIdx.x;
    int d    = (hh << 6) | t;                 // feature index
    const int2* eb = epack + ((size_t)c << PAD_SHIFT);
    float di = dinv[c];
    int tot = 0;
#pragma unroll
    for (int x = 0; x < 8; ++x) {
        int mx = cnt8[x * CSTRIDE + c];
        if (t < mx) {
            int2 v = eb[x * SEG + t];
            s_src[tot + t] = v.x;
            s_n[tot + t]   = dinv[v.x] * __int_as_float(v.y);
        }
        tot += mx;
    }
    __syncthreads();
    int m = tot;
    float acc = di * H[(size_t)c * D + d];    // self-loop (x di in epilogue)
    int jj = 0;
    for (; jj + 8 <= m; jj += 8) {
#pragma unroll
        for (int k = 0; k < 8; ++k)
            acc = fmaf(s_n[jj + k], H[(size_t)s_src[jj + k] * D + d], acc);
    }
    for (; jj < m; ++jj)
        acc = fmaf(s_n[jj], H[(size_t)s_src[jj] * D + d], acc);
    out[(size_t)c * D + d] = fmaxf(fmaf(di, acc, bias[d]), 0.0f);
}

// ---- launch -------------------------------------------------------------

extern "C" void kernel_launch(void* const* d_in, const int* in_sizes, int n_in,
                              void* d_out, int out_size, void* d_ws, size_t ws_size,
                              hipStream_t stream) {
    const float* x  = (const float*)d_in[0];
    const int*   ei = (const int*)  d_in[1];   // [2, NE]
    const float* ew = (const float*)d_in[2];
    const float* W1 = (const float*)d_in[3];
    const float* b1 = (const float*)d_in[4];
    const float* W2 = (const float*)d_in[5];
    const float* b2 = (const float*)d_in[6];
    float* out = (float*)d_out;

    char* ws = (char*)d_ws;
    size_t off = 0;
    auto alloc = [&](size_t bytes) {
        void* p = ws + off;
        off = (off + bytes + 255) & ~(size_t)255;
        return p;
    };
    int*   cnt8  = (int*)  alloc(8 * CSTRIDE * 4);
    float* dinv  = (float*)alloc(NN * 4);
    int2*  epack = (int2*) alloc(((size_t)NN << PAD_SHIFT) * 8);
    float* h     = (float*)alloc((size_t)NN * D * 4);
    float* g     = (float*)alloc((size_t)NN * D * 4);

    zero_kernel<<<(8 * CSTRIDE + 255) / 256, 256, 0, stream>>>(cnt8, 8 * CSTRIDE);
    fused_gemm_cs_kernel<<<GEMM_BLOCKS + COUNT_BLOCKS, 256, 0, stream>>>(
        x, W1, h, ei, ew, cnt8, epack);
    degdinv_kernel<<<(NN + 3) / 4, 256, 0, stream>>>(cnt8, epack, dinv);

    agg_half_kernel<<<NN * 2, 64, 0, stream>>>(h, cnt8, epack, dinv, b1, g);
    gemm_kernel    <<<(NN + 31) / 32, 256, 0, stream>>>(g, W2, h);
    agg_half_kernel<<<NN * 2, 64, 0, stream>>>(h, cnt8, epack, dinv, b2, out);
}

// Round 15
// 153.138 us; speedup vs baseline: 1.0203x; 1.0203x over previous
//
#include <hip/hip_runtime.h>
#include <hip/hip_cooperative_groups.h>

namespace cg = cooperative_groups;

#define NN 10000
#define NE 640000
#define D  128
#define SEG 32                   // slots per (node,XCD); Poisson(8) P(>=32) ~ 1e-10/pair
#define PAD_SHIFT 8              // 256 slots/node = 8 segments x 32
#define CSTRIDE 10240
#define GEMM_TILES 313           // ceil(NN/32)
#define NCHUNK 625               // 1024-edge count chunks (625*1024 == NE)
#define COOP_GRID 1024           // 4 blocks/CU on 256 CUs

// physical XCD id of the wave (0..7 on MI355X)
__device__ __forceinline__ int xcc_id() {
    unsigned x;
    asm volatile("s_getreg_b32 %0, hwreg(HW_REG_XCC_ID)" : "=s"(x));
    return (int)(x & 7);
}

// ---- 32-row GEMM tile (256 thr): H[tile rows] = X[tile rows] @ W --------
__device__ __forceinline__ void gemm_tile(const float* __restrict__ X,
                                          const float* __restrict__ W,
                                          float* __restrict__ H,
                                          int tile, int t, float (*xs)[D]) {
    int d  = t & 127;
    int rh = t >> 7;
    int r0 = tile * 32;
#pragma unroll
    for (int r = 0; r < 16; ++r) {
        int rr = r0 + rh * 16 + r;
        xs[rh * 16 + r][d] = (rr < NN) ? X[(size_t)rr * D + d] : 0.0f;
    }
    __syncthreads();
    float acc[16];
#pragma unroll
    for (int r = 0; r < 16; ++r) acc[r] = 0.0f;
    for (int k = 0; k < D; k += 4) {
        float w0 = W[(k + 0) * D + d];
        float w1 = W[(k + 1) * D + d];
        float w2 = W[(k + 2) * D + d];
        float w3 = W[(k + 3) * D + d];
#pragma unroll
        for (int r = 0; r < 16; ++r) {
            float4 xv = *reinterpret_cast<const float4*>(&xs[rh * 16 + r][k]);
            acc[r] = fmaf(xv.x, w0, acc[r]);
            acc[r] = fmaf(xv.y, w1, acc[r]);
            acc[r] = fmaf(xv.z, w2, acc[r]);
            acc[r] = fmaf(xv.w, w3, acc[r]);
        }
    }
#pragma unroll
    for (int r = 0; r < 16; ++r) {
        int rr = r0 + rh * 16 + r;
        if (rr < NN) H[(size_t)rr * D + d] = acc[r];
    }
    __syncthreads();
}

// ---- phase: zero per-XCD counters ---------------------------------------
__device__ __forceinline__ void phase_zero(int bid, int t, int grid,
                                           int* __restrict__ cnt8) {
    for (int i = bid * 256 + t; i < 8 * CSTRIDE; i += grid * 256) cnt8[i] = 0;
}

// ---- phase: gemm1 (tiles) + count&scatter into fixed segments -----------
__device__ __forceinline__ void phase_build(int bid, int t, int grid,
                                            const float* __restrict__ X,
                                            const float* __restrict__ W1,
                                            float* __restrict__ H,
                                            const int* __restrict__ ei,
                                            const float* __restrict__ ew,
                                            int* __restrict__ cnt8,
                                            int2* __restrict__ epack,
                                            float (*xs)[D]) {
    if (bid < GEMM_TILES) {
        gemm_tile(X, W1, H, bid, t, xs);
    } else {
        int nb = grid - GEMM_TILES;
        for (int chunk = bid - GEMM_TILES; chunk < NCHUNK; chunk += nb) {
            int e0 = chunk * 1024 + t;
            int x  = xcc_id();
            int* mycnt = cnt8 + x * CSTRIDE;
            int   c[4], sR[4];
            float w[4];
#pragma unroll
            for (int k = 0; k < 4; ++k) {
                int e = e0 + k * 256;
                c[k]  = ei[NE + e];
                sR[k] = ei[e];
                w[k]  = ew[e];
            }
            int lr[4];
#pragma unroll
            for (int k = 0; k < 4; ++k) lr[k] = atomicAdd(&mycnt[c[k]], 1);
#pragma unroll
            for (int k = 0; k < 4; ++k) {
                if (lr[k] < SEG) {           // overflow guard (P ~ 1e-10)
                    int2 v;
                    v.x = sR[k];
                    v.y = __float_as_int(w[k]);
                    epack[((size_t)c[k] << PAD_SHIFT) + x * SEG + lr[k]] = v;
                }
            }
        }
    }
}

// ---- phase: deg -> dinv (64-lane group per node, parallel counts) -------
__device__ __forceinline__ void phase_deg(int bid, int t, int grid,
                                          const int* __restrict__ cnt8,
                                          const int2* __restrict__ epack,
                                          float* __restrict__ dinv) {
    int lane = t & 63;
    for (int node = bid * 4 + (t >> 6); node < NN; node += grid * 4) {
        int mxv = (lane < 8) ? min(cnt8[lane * CSTRIDE + node], SEG) : 0;
        const int2* eb = epack + ((size_t)node << PAD_SHIFT);
        float s = 0.0f;
#pragma unroll
        for (int x = 0; x < 8; ++x) {
            int mxx = __shfl(mxv, x);
            if (lane < mxx) s += __int_as_float(eb[x * SEG + lane].y);
        }
#pragma unroll
        for (int off = 32; off; off >>= 1) s += __shfl_down(s, off);
        if (lane == 0) dinv[node] = rsqrtf(s + 1.0f);   // +1 = self loop
    }
}

// ---- phase: aggregate, half-feature per 64-lane group, XCD-parity -------
// bid parity p selects feature half (round-robin bid%8 -> XCD keeps each
// XCD's gather set at 2.56MB -> fits the 4MB L2). Parallel 8-seg staging.
__device__ __forceinline__ void phase_agg(int bid, int t, int grid,
                                          const float* __restrict__ Hsrc,
                                          const int* __restrict__ cnt8,
                                          const int2* __restrict__ epack,
                                          const float* __restrict__ dinv,
                                          const float* __restrict__ bias,
                                          float* __restrict__ outp,
                                          float (*xs)[D]) {
    int p    = bid & 1;
    int r    = bid >> 1;
    int half = grid >> 1;
    int gg   = t >> 6;
    int lane = t & 63;
    int d    = (p << 6) | lane;
    int*   s_src = ((int*)xs) + gg * 256;
    float* s_n   = ((float*)xs) + 1024 + gg * 256;
    float bd = bias[d];
    for (int cbase = r * 4; cbase < NN; cbase += half * 4) {   // uniform per block
        int c = cbase + gg;
        bool act = (c < NN);
        int tot = 0;
        float di = 0.0f;
        if (act) {
            int mxv = (lane < 8) ? min(cnt8[lane * CSTRIDE + c], SEG) : 0;
            const int2* eb = epack + ((size_t)c << PAD_SHIFT);
            int mx[8], pre[8];
#pragma unroll
            for (int x = 0; x < 8; ++x) { mx[x] = __shfl(mxv, x); pre[x] = tot; tot += mx[x]; }
#pragma unroll
            for (int x = 0; x < 8; ++x) {
                if (lane < mx[x]) {
                    int2 v = eb[x * SEG + lane];
                    int pp = pre[x] + lane;
                    s_src[pp] = v.x;
                    s_n[pp]   = dinv[v.x] * __int_as_float(v.y);
                }
            }
            di = dinv[c];
        }
        __syncthreads();
        if (act) {
            float acc = di * Hsrc[(size_t)c * D + d];    // self-loop
            int jj = 0;
            for (; jj + 8 <= tot; jj += 8) {
#pragma unroll
                for (int k = 0; k < 8; ++k)
                    acc = fmaf(s_n[jj + k], Hsrc[(size_t)s_src[jj + k] * D + d], acc);
            }
            for (; jj < tot; ++jj)
                acc = fmaf(s_n[jj], Hsrc[(size_t)s_src[jj] * D + d], acc);
            outp[(size_t)c * D + d] = fmaxf(fmaf(di, acc, bd), 0.0f);
        }
        __syncthreads();
    }
}

// ---- cooperative mega-kernel --------------------------------------------

__global__ __launch_bounds__(256, 4) void mega_kernel(const float* __restrict__ X,
                                                      const int* __restrict__ ei,
                                                      const float* __restrict__ ew,
                                                      const float* __restrict__ W1,
                                                      const float* __restrict__ b1,
                                                      const float* __restrict__ W2,
                                                      const float* __restrict__ b2,
                                                      float* __restrict__ out,
                                                      int* __restrict__ cnt8,
                                                      float* __restrict__ dinv,
                                                      int2* __restrict__ epack,
                                                      float* __restrict__ h,
                                                      float* __restrict__ g) {
    cg::grid_group grid = cg::this_grid();
    __shared__ float xs[32][D];
    int bid = blockIdx.x, t = threadIdx.x, gs = gridDim.x;

    phase_zero(bid, t, gs, cnt8);
    __threadfence(); grid.sync();
    phase_build(bid, t, gs, X, W1, h, ei, ew, cnt8, epack, xs);
    __threadfence(); grid.sync();
    phase_deg(bid, t, gs, cnt8, epack, dinv);
    __threadfence(); grid.sync();
    phase_agg(bid, t, gs, h, cnt8, epack, dinv, b1, g, xs);
    __threadfence(); grid.sync();
    if (bid < GEMM_TILES) gemm_tile(g, W2, h, bid, t, xs);
    __threadfence(); grid.sync();
    phase_agg(bid, t, gs, h, cnt8, epack, dinv, b2, out, xs);
}

// ---- fallback wrappers (same phase functions, separate dispatches) ------

__global__ __launch_bounds__(256) void k_zero(int* cnt8) {
    phase_zero(blockIdx.x, threadIdx.x, gridDim.x, cnt8);
}
__global__ __launch_bounds__(256, 4) void k_build(const float* X, const float* W1,
                                                  float* H, const int* ei,
                                                  const float* ew, int* cnt8,
                                                  int2* epack) {
    __shared__ float xs[32][D];
    phase_build(blockIdx.x, threadIdx.x, gridDim.x, X, W1, H, ei, ew, cnt8, epack, xs);
}
__global__ __launch_bounds__(256) void k_deg(const int* cnt8, const int2* epack,
                                             float* dinv) {
    phase_deg(blockIdx.x, threadIdx.x, gridDim.x, cnt8, epack, dinv);
}
__global__ __launch_bounds__(256, 4) void k_agg(const float* Hsrc, const int* cnt8,
                                                const int2* epack, const float* dinv,
                                                const float* bias, float* outp) {
    __shared__ float xs[32][D];
    phase_agg(blockIdx.x, threadIdx.x, gridDim.x, Hsrc, cnt8, epack, dinv, bias, outp, xs);
}
__global__ __launch_bounds__(256, 4) void k_gemm(const float* X, const float* W,
                                                 float* H) {
    __shared__ float xs[32][D];
    for (int tile = blockIdx.x; tile < GEMM_TILES; tile += gridDim.x)
        gemm_tile(X, W, H, tile, threadIdx.x, xs);
}

// ---- launch -------------------------------------------------------------

extern "C" void kernel_launch(void* const* d_in, const int* in_sizes, int n_in,
                              void* d_out, int out_size, void* d_ws, size_t ws_size,
                              hipStream_t stream) {
    const float* x  = (const float*)d_in[0];
    const int*   ei = (const int*)  d_in[1];   // [2, NE]
    const float* ew = (const float*)d_in[2];
    const float* W1 = (const float*)d_in[3];
    const float* b1 = (const float*)d_in[4];
    const float* W2 = (const float*)d_in[5];
    const float* b2 = (const float*)d_in[6];
    float* out = (float*)d_out;

    char* ws = (char*)d_ws;
    size_t off = 0;
    auto alloc = [&](size_t bytes) {
        void* p = ws + off;
        off = (off + bytes + 255) & ~(size_t)255;
        return p;
    };
    int*   cnt8  = (int*)  alloc(8 * CSTRIDE * 4);
    float* dinv  = (float*)alloc(NN * 4);
    int2*  epack = (int2*) alloc(((size_t)NN << PAD_SHIFT) * 8);
    float* h     = (float*)alloc((size_t)NN * D * 4);
    float* g     = (float*)alloc((size_t)NN * D * 4);

    // host-side occupancy guard (graph-safe query, deterministic)
    int maxPerCU = 0;
    hipError_t oe = hipOccupancyMaxActiveBlocksPerMultiprocessor(&maxPerCU,
                                                                 mega_kernel, 256, 0);
    bool coop = (oe == hipSuccess) && (maxPerCU * 256 >= COOP_GRID);
    if (coop) {
        void* args[] = {(void*)&x, (void*)&ei, (void*)&ew, (void*)&W1, (void*)&b1,
                        (void*)&W2, (void*)&b2, (void*)&out, (void*)&cnt8,
                        (void*)&dinv, (void*)&epack, (void*)&h, (void*)&g};
        hipError_t le = hipLaunchCooperativeKernel((const void*)mega_kernel,
                                                   dim3(COOP_GRID), dim3(256),
                                                   args, 0, stream);
        if (le == hipSuccess) return;
    }
    // fallback: same phases as separate dispatches
    k_zero <<<320, 256, 0, stream>>>(cnt8);
    k_build<<<GEMM_TILES + NCHUNK, 256, 0, stream>>>(x, W1, h, ei, ew, cnt8, epack);
    k_deg  <<<2500, 256, 0, stream>>>(cnt8, epack, dinv);
    k_agg  <<<5000, 256, 0, stream>>>(h, cnt8, epack, dinv, b1, g);
    k_gemm <<<GEMM_TILES, 256, 0, stream>>>(g, W2, h);
    k_agg  <<<5000, 256, 0, stream>>>(h, cnt8, epack, dinv, b2, out);
}

// Round 16
// 150.517 us; speedup vs baseline: 1.0380x; 1.0174x over previous
//
#include <hip/hip_runtime.h>

#define NN 10000
#define NE 640000
#define D  128
#define SEG 32                   // slots per (node,XCD); Poisson(8) P(>=32) ~ 1e-10/pair
#define PAD_SHIFT 8              // 256 slots/node = 8 segments x 32
#define GEMM_BLOCKS ((NN + 31) / 32)
#define CSTRIDE 10240
#define COUNT_BLOCKS (NE / 1024) // 625 blocks x 256 thr x 4 edges

// physical XCD id of the wave (0..7 on MI355X)
__device__ __forceinline__ int xcc_id() {
    unsigned x;
    asm volatile("s_getreg_b32 %0, hwreg(HW_REG_XCC_ID)" : "=s"(x));
    return (int)(x & 7);
}

// ---- zero the per-XCD counter replicas ----------------------------------

__global__ __launch_bounds__(256) void zero_kernel(int* __restrict__ p, int n) {
    int i = blockIdx.x * 256 + threadIdx.x;
    if (i < n) p[i] = 0;
}

// ---- fused: gemm1 + count&scatter (fixed per-XCD segments) --------------
// slot = (c<<8) + xcd*32 + local_rank, computed in the same thread that did
// the atomic; 4-deep batching overlaps the atomic->store chains (R13-meas).

__global__ __launch_bounds__(256) void fused_gemm_cs_kernel(const float* __restrict__ X,
                                                            const float* __restrict__ W,
                                                            float* __restrict__ H,
                                                            const int* __restrict__ ei,
                                                            const float* __restrict__ ew,
                                                            int* __restrict__ cnt8,
                                                            int2* __restrict__ epack) {
    int bid = blockIdx.x;
    if (bid < GEMM_BLOCKS) {
        __shared__ float xs[32][D];
        int t  = threadIdx.x;
        int d  = t & 127;
        int rh = t >> 7;
        int r0 = bid * 32;
#pragma unroll
        for (int r = 0; r < 16; ++r) {
            int rr = r0 + rh * 16 + r;
            xs[rh * 16 + r][d] = (rr < NN) ? X[(size_t)rr * D + d] : 0.0f;
        }
        __syncthreads();
        float acc[16];
#pragma unroll
        for (int r = 0; r < 16; ++r) acc[r] = 0.0f;
        for (int k = 0; k < D; k += 4) {
            float w0 = W[(k + 0) * D + d];
            float w1 = W[(k + 1) * D + d];
            float w2 = W[(k + 2) * D + d];
            float w3 = W[(k + 3) * D + d];
#pragma unroll
            for (int r = 0; r < 16; ++r) {
                float4 xv = *reinterpret_cast<const float4*>(&xs[rh * 16 + r][k]);
                acc[r] = fmaf(xv.x, w0, acc[r]);
                acc[r] = fmaf(xv.y, w1, acc[r]);
                acc[r] = fmaf(xv.z, w2, acc[r]);
                acc[r] = fmaf(xv.w, w3, acc[r]);
            }
        }
#pragma unroll
        for (int r = 0; r < 16; ++r) {
            int rr = r0 + rh * 16 + r;
            if (rr < NN) H[(size_t)rr * D + d] = acc[r];
        }
    } else {
        int e0 = (bid - GEMM_BLOCKS) * 1024 + threadIdx.x;
        int x  = xcc_id();
        int* mycnt = cnt8 + x * CSTRIDE;
        int   c[4], s[4];
        float w[4];
#pragma unroll
        for (int k = 0; k < 4; ++k) {
            int e = e0 + k * 256;          // 625*1024 == NE exactly
            c[k] = ei[NE + e];
            s[k] = ei[e];
            w[k] = ew[e];
        }
        int lr[4];
#pragma unroll
        for (int k = 0; k < 4; ++k) lr[k] = atomicAdd(&mycnt[c[k]], 1);
#pragma unroll
        for (int k = 0; k < 4; ++k) {
            if (lr[k] < SEG) {             // overflow guard (P ~ 1e-10/pair)
                int2 v;
                v.x = s[k];
                v.y = __float_as_int(w[k]);
                epack[((size_t)c[k] << PAD_SHIFT) + x * SEG + lr[k]] = v;
            }
        }
    }
}

// ---- deg -> dinv: 64-lane group per node, PARALLEL segment staging ------

__global__ __launch_bounds__(256) void degdinv_kernel(const int* __restrict__ cnt8,
                                                      const int2* __restrict__ epack,
                                                      float* __restrict__ dinv) {
    int node = blockIdx.x * 4 + (threadIdx.x >> 6);
    if (node >= NN) return;
    int lane = threadIdx.x & 63;
    int mxv = (lane < 8) ? min(cnt8[lane * CSTRIDE + node], SEG) : 0;
    const int2* eb = epack + ((size_t)node << PAD_SHIFT);
    float s = 0.0f;
#pragma unroll
    for (int x = 0; x < 8; ++x) {
        int mxx = __shfl(mxv, x);
        if (lane < mxx) s += __int_as_float(eb[x * SEG + lane].y);
    }
#pragma unroll
    for (int off = 32; off; off >>= 1) s += __shfl_down(s, off);
    if (lane == 0) dinv[node] = rsqrtf(s + 1.0f);      // +1 = self loop
}

// ---- plain gemm (layer 2): 32 rows/block, 256 threads -------------------

__global__ __launch_bounds__(256) void gemm_kernel(const float* __restrict__ X,
                                                   const float* __restrict__ W,
                                                   float* __restrict__ H) {
    __shared__ float xs[32][D];
    int t  = threadIdx.x;
    int d  = t & 127;
    int rh = t >> 7;
    int r0 = blockIdx.x * 32;
#pragma unroll
    for (int r = 0; r < 16; ++r) {
        int rr = r0 + rh * 16 + r;
        xs[rh * 16 + r][d] = (rr < NN) ? X[(size_t)rr * D + d] : 0.0f;
    }
    __syncthreads();
    float acc[16];
#pragma unroll
    for (int r = 0; r < 16; ++r) acc[r] = 0.0f;
    for (int k = 0; k < D; k += 4) {
        float w0 = W[(k + 0) * D + d];
        float w1 = W[(k + 1) * D + d];
        float w2 = W[(k + 2) * D + d];
        float w3 = W[(k + 3) * D + d];
#pragma unroll
        for (int r = 0; r < 16; ++r) {
            float4 xv = *reinterpret_cast<const float4*>(&xs[rh * 16 + r][k]);
            acc[r] = fmaf(xv.x, w0, acc[r]);
            acc[r] = fmaf(xv.y, w1, acc[r]);
            acc[r] = fmaf(xv.z, w2, acc[r]);
            acc[r] = fmaf(xv.w, w3, acc[r]);
        }
    }
#pragma unroll
    for (int r = 0; r < 16; ++r) {
        int rr = r0 + rh * 16 + r;
        if (rr < NN) H[(size_t)rr * D + d] = acc[r];
    }
}

// ---- aggregate: half-feature per block, XCD-parity, parallel staging ----
// Block i -> (node c, half hh), i = (c/4)*8 + (c%4)*2 + hh: on round-robin
// blockIdx%8 -> XCD dispatch, even XCDs gather only H[:,0:64] (2.56MB),
// odd XCDs H[:,64:128] -> per-XCD gather set fits the 4MB L2.

__global__ __launch_bounds__(64) void agg_half_kernel(const float* __restrict__ H,
                                                      const int* __restrict__ cnt8,
                                                      const int2* __restrict__ epack,
                                                      const float* __restrict__ dinv,
                                                      const float* __restrict__ bias,
                                                      float* __restrict__ out) {
    __shared__ int   s_src[256];
    __shared__ float s_n[256];
    int i    = blockIdx.x;
    int slot = i & 7;
    int hh   = slot & 1;
    int c    = (i >> 3) * 4 + (slot >> 1);
    int t    = threadIdx.x;
    int d    = (hh << 6) | t;                 // feature index
    const int2* eb = epack + ((size_t)c << PAD_SHIFT);
    float di = dinv[c];
    // parallel 8-segment staging: counts via lanes 0..7 + shfl broadcast
    int mxv = (t < 8) ? min(cnt8[t * CSTRIDE + c], SEG) : 0;
    int mx[8], pre[8];
    int tot = 0;
#pragma unroll
    for (int x = 0; x < 8; ++x) { mx[x] = __shfl(mxv, x); pre[x] = tot; tot += mx[x]; }
#pragma unroll
    for (int x = 0; x < 8; ++x) {
        if (t < mx[x]) {
            int2 v = eb[x * SEG + t];
            int pp = pre[x] + t;
            s_src[pp] = v.x;
            s_n[pp]   = dinv[v.x] * __int_as_float(v.y);
        }
    }
    __syncthreads();
    int m = tot;
    float acc = di * H[(size_t)c * D + d];    // self-loop (x di in epilogue)
    int jj = 0;
    for (; jj + 8 <= m; jj += 8) {
#pragma unroll
        for (int k = 0; k < 8; ++k)
            acc = fmaf(s_n[jj + k], H[(size_t)s_src[jj + k] * D + d], acc);
    }
    for (; jj < m; ++jj)
        acc = fmaf(s_n[jj], H[(size_t)s_src[jj] * D + d], acc);
    out[(size_t)c * D + d] = fmaxf(fmaf(di, acc, bias[d]), 0.0f);
}

// ---- launch -------------------------------------------------------------

extern "C" void kernel_launch(void* const* d_in, const int* in_sizes, int n_in,
                              void* d_out, int out_size, void* d_ws, size_t ws_size,
                              hipStream_t stream) {
    const float* x  = (const float*)d_in[0];
    const int*   ei = (const int*)  d_in[1];   // [2, NE]
    const float* ew = (const float*)d_in[2];
    const float* W1 = (const float*)d_in[3];
    const float* b1 = (const float*)d_in[4];
    const float* W2 = (const float*)d_in[5];
    const float* b2 = (const float*)d_in[6];
    float* out = (float*)d_out;

    char* ws = (char*)d_ws;
    size_t off = 0;
    auto alloc = [&](size_t bytes) {
        void* p = ws + off;
        off = (off + bytes + 255) & ~(size_t)255;
        return p;
    };
    int*   cnt8  = (int*)  alloc(8 * CSTRIDE * 4);
    float* dinv  = (float*)alloc(NN * 4);
    int2*  epack = (int2*) alloc(((size_t)NN << PAD_SHIFT) * 8);
    float* h     = (float*)alloc((size_t)NN * D * 4);
    float* g     = (float*)alloc((size_t)NN * D * 4);

    zero_kernel<<<(8 * CSTRIDE + 255) / 256, 256, 0, stream>>>(cnt8, 8 * CSTRIDE);
    fused_gemm_cs_kernel<<<GEMM_BLOCKS + COUNT_BLOCKS, 256, 0, stream>>>(
        x, W1, h, ei, ew, cnt8, epack);
    degdinv_kernel<<<(NN + 3) / 4, 256, 0, stream>>>(cnt8, epack, dinv);

    agg_half_kernel<<<NN * 2, 64, 0, stream>>>(h, cnt8, epack, dinv, b1, g);
    gemm_kernel    <<<(NN + 31) / 32, 256, 0, stream>>>(g, W2, h);
    agg_half_kernel<<<NN * 2, 64, 0, stream>>>(h, cnt8, epack, dinv, b2, out);
}

// Round 17
// 137.597 us; speedup vs baseline: 1.1355x; 1.0939x over previous
//
#include <hip/hip_runtime.h>

#define NN 10000
#define NE 640000
#define D  128
#define PAD_SHIFT 7              // 128 slots/node; P(deg>=128 | mean 64) ~ 3e-13/node
#define GEMM_BLOCKS ((NN + 31) / 32)   // 313
#define COUNT_BLOCKS (NE / 1024)       // 625 blocks x 256 thr x 4 edges

// ---- zero the per-node counters ----------------------------------------

__global__ __launch_bounds__(256) void zero_kernel(int* __restrict__ p, int n) {
    int i = blockIdx.x * 256 + threadIdx.x;
    if (i < n) p[i] = 0;
}

// ---- fused: gemm1 + count&scatter into CONTIGUOUS padded CSR ------------
// slot = (c<<7) + lr from ONE global counter (per-XCD split proven useless
// for atomic cost, R6/R7; contiguous layout proven vital for consumers,
// R16). 4-deep batching overlaps the atomic->store chains (R13-measured).

__global__ __launch_bounds__(256) void fused_gemm_cs_kernel(const float* __restrict__ X,
                                                            const float* __restrict__ W,
                                                            float* __restrict__ H,
                                                            const int* __restrict__ ei,
                                                            const float* __restrict__ ew,
                                                            int* __restrict__ cnt,
                                                            int2* __restrict__ epack) {
    int bid = blockIdx.x;
    if (bid < GEMM_BLOCKS) {
        __shared__ float xs[32][D];
        int t  = threadIdx.x;
        int d  = t & 127;
        int rh = t >> 7;
        int r0 = bid * 32;
#pragma unroll
        for (int r = 0; r < 16; ++r) {
            int rr = r0 + rh * 16 + r;
            xs[rh * 16 + r][d] = (rr < NN) ? X[(size_t)rr * D + d] : 0.0f;
        }
        __syncthreads();
        float acc[16];
#pragma unroll
        for (int r = 0; r < 16; ++r) acc[r] = 0.0f;
        for (int k = 0; k < D; k += 4) {
            float w0 = W[(k + 0) * D + d];
            float w1 = W[(k + 1) * D + d];
            float w2 = W[(k + 2) * D + d];
            float w3 = W[(k + 3) * D + d];
#pragma unroll
            for (int r = 0; r < 16; ++r) {
                float4 xv = *reinterpret_cast<const float4*>(&xs[rh * 16 + r][k]);
                acc[r] = fmaf(xv.x, w0, acc[r]);
                acc[r] = fmaf(xv.y, w1, acc[r]);
                acc[r] = fmaf(xv.z, w2, acc[r]);
                acc[r] = fmaf(xv.w, w3, acc[r]);
            }
        }
#pragma unroll
        for (int r = 0; r < 16; ++r) {
            int rr = r0 + rh * 16 + r;
            if (rr < NN) H[(size_t)rr * D + d] = acc[r];
        }
    } else {
        int e0 = (bid - GEMM_BLOCKS) * 1024 + threadIdx.x;
        int   c[4], s[4];
        float w[4];
#pragma unroll
        for (int k = 0; k < 4; ++k) {
            int e = e0 + k * 256;          // 625*1024 == NE exactly
            c[k] = ei[NE + e];
            s[k] = ei[e];
            w[k] = ew[e];
        }
        int lr[4];
#pragma unroll
        for (int k = 0; k < 4; ++k) lr[k] = atomicAdd(&cnt[c[k]], 1);
#pragma unroll
        for (int k = 0; k < 4; ++k) {
            if (lr[k] < (1 << PAD_SHIFT)) {          // overflow guard
                int2 v;
                v.x = s[k];
                v.y = __float_as_int(w[k]);
                epack[((size_t)c[k] << PAD_SHIFT) + lr[k]] = v;
            }
        }
    }
}

// ---- deg -> dinv from contiguous padded CSR, wave per node --------------

__global__ __launch_bounds__(256) void degdinv_kernel(const int* __restrict__ cnt,
                                                      const int2* __restrict__ epack,
                                                      float* __restrict__ dinv) {
    int node = blockIdx.x * 4 + (threadIdx.x >> 6);
    if (node >= NN) return;
    int lane = threadIdx.x & 63;
    int m = min(cnt[node], 1 << PAD_SHIFT);
    const int2* eb = epack + ((size_t)node << PAD_SHIFT);
    float s = 0.0f;
    for (int j = lane; j < m; j += 64) s += __int_as_float(eb[j].y);
#pragma unroll
    for (int off = 32; off; off >>= 1) s += __shfl_down(s, off);
    if (lane == 0) dinv[node] = rsqrtf(s + 1.0f);      // +1 = self loop
}

// ---- plain gemm (layer 2): 32 rows/block, 256 threads -------------------

__global__ __launch_bounds__(256) void gemm_kernel(const float* __restrict__ X,
                                                   const float* __restrict__ W,
                                                   float* __restrict__ H) {
    __shared__ float xs[32][D];
    int t  = threadIdx.x;
    int d  = t & 127;
    int rh = t >> 7;
    int r0 = blockIdx.x * 32;
#pragma unroll
    for (int r = 0; r < 16; ++r) {
        int rr = r0 + rh * 16 + r;
        xs[rh * 16 + r][d] = (rr < NN) ? X[(size_t)rr * D + d] : 0.0f;
    }
    __syncthreads();
    float acc[16];
#pragma unroll
    for (int r = 0; r < 16; ++r) acc[r] = 0.0f;
    for (int k = 0; k < D; k += 4) {
        float w0 = W[(k + 0) * D + d];
        float w1 = W[(k + 1) * D + d];
        float w2 = W[(k + 2) * D + d];
        float w3 = W[(k + 3) * D + d];
#pragma unroll
        for (int r = 0; r < 16; ++r) {
            float4 xv = *reinterpret_cast<const float4*>(&xs[rh * 16 + r][k]);
            acc[r] = fmaf(xv.x, w0, acc[r]);
            acc[r] = fmaf(xv.y, w1, acc[r]);
            acc[r] = fmaf(xv.z, w2, acc[r]);
            acc[r] = fmaf(xv.w, w3, acc[r]);
        }
    }
#pragma unroll
    for (int r = 0; r < 16; ++r) {
        int rr = r0 + rh * 16 + r;
        if (rr < NN) H[(size_t)rr * D + d] = acc[r];
    }
}

// ---- aggregate: half-feature per block, XCD-parity mapped (R12) ---------
// Block i -> (node c, half hh), i = (c/4)*8 + (c%4)*2 + hh: on round-robin
// blockIdx%8 -> XCD dispatch, even XCDs gather only H[:,0:64] (2.56MB),
// odd XCDs H[:,64:128] -> per-XCD gather set fits the 4MB L2.

__global__ __launch_bounds__(64) void agg_half_kernel(const float* __restrict__ H,
                                                      const int* __restrict__ cnt,
                                                      const int2* __restrict__ epack,
                                                      const float* __restrict__ dinv,
                                                      const float* __restrict__ bias,
                                                      float* __restrict__ out) {
    __shared__ int   s_src[128];
    __shared__ float s_n[128];
    int i    = blockIdx.x;
    int slot = i & 7;
    int hh   = slot & 1;
    int c    = (i >> 3) * 4 + (slot >> 1);
    int t    = threadIdx.x;
    int d    = (hh << 6) | t;                 // feature index
    int m    = min(cnt[c], 1 << PAD_SHIFT);
    const int2* eb = epack + ((size_t)c << PAD_SHIFT);
    float di = dinv[c];
    for (int j = t; j < m; j += 64) {
        int2 v = eb[j];
        s_src[j] = v.x;
        s_n[j]   = dinv[v.x] * __int_as_float(v.y);
    }
    __syncthreads();
    float acc = di * H[(size_t)c * D + d];    // self-loop (x di in epilogue)
    int jj = 0;
    for (; jj + 8 <= m; jj += 8) {
#pragma unroll
        for (int k = 0; k < 8; ++k)
            acc = fmaf(s_n[jj + k], H[(size_t)s_src[jj + k] * D + d], acc);
    }
    for (; jj < m; ++jj)
        acc = fmaf(s_n[jj], H[(size_t)s_src[jj] * D + d], acc);
    out[(size_t)c * D + d] = fmaxf(fmaf(di, acc, bias[d]), 0.0f);
}

// ---- launch -------------------------------------------------------------

extern "C" void kernel_launch(void* const* d_in, const int* in_sizes, int n_in,
                              void* d_out, int out_size, void* d_ws, size_t ws_size,
                              hipStream_t stream) {
    const float* x  = (const float*)d_in[0];
    const int*   ei = (const int*)  d_in[1];   // [2, NE]
    const float* ew = (const float*)d_in[2];
    const float* W1 = (const float*)d_in[3];
    const float* b1 = (const float*)d_in[4];
    const float* W2 = (const float*)d_in[5];
    const float* b2 = (const float*)d_in[6];
    float* out = (float*)d_out;

    char* ws = (char*)d_ws;
    size_t off = 0;
    auto alloc = [&](size_t bytes) {
        void* p = ws + off;
        off = (off + bytes + 255) & ~(size_t)255;
        return p;
    };
    int*   cnt   = (int*)  alloc(NN * 4);
    float* dinv  = (float*)alloc(NN * 4);
    int2*  epack = (int2*) alloc(((size_t)NN << PAD_SHIFT) * 8);
    float* h     = (float*)alloc((size_t)NN * D * 4);
    float* g     = (float*)alloc((size_t)NN * D * 4);

    zero_kernel<<<(NN + 255) / 256, 256, 0, stream>>>(cnt, NN);
    fused_gemm_cs_kernel<<<GEMM_BLOCKS + COUNT_BLOCKS, 256, 0, stream>>>(
        x, W1, h, ei, ew, cnt, epack);
    degdinv_kernel<<<(NN + 3) / 4, 256, 0, stream>>>(cnt, epack, dinv);

    agg_half_kernel<<<NN * 2, 64, 0, stream>>>(h, cnt, epack, dinv, b1, g);
    gemm_kernel    <<<(NN + 31) / 32, 256, 0, stream>>>(g, W2, h);
    agg_half_kernel<<<NN * 2, 64, 0, stream>>>(h, cnt, epack, dinv, b2, out);
}